// Round 1
// baseline (81.481 us; speedup 1.0000x reference)
//
#include <hip/hip_runtime.h>
#include <stdint.h>

// SampleChamfer: out = sum_i min_k ||pa_i - pb_k||^2
// pa_i = a[:, a_idx[i]], pb_k = b[:, b_idx[k]], fp32 scalar out.
//
// Decomposition: d = sq_a[i] + (sq_b[k] - 2*dot(pb_k, pa_i)).
// Kernel 1 computes cand = sq_b - 2*dot, min over k, combining across
// b-chunk blocks with atomicMin on an order-preserving uint encoding.
// Kernel 2 decodes, adds sq_a[i], and sum-reduces to d_out.

#define BLOCK   256
#define NPTS_A  8     // a-points per thread (register tile)
#define BPTS    128   // b-points per block (LDS tile)

// Order-preserving map float -> uint32 (monotone for ALL floats incl. negatives)
__device__ __forceinline__ unsigned enc_f32(float f) {
    unsigned u = __float_as_uint(f);
    return (u & 0x80000000u) ? ~u : (u | 0x80000000u);
}
__device__ __forceinline__ float dec_f32(unsigned u) {
    return (u & 0x80000000u) ? __uint_as_float(u & 0x7FFFFFFFu)
                             : __uint_as_float(~u);
}

__global__ __launch_bounds__(BLOCK)
void chamfer_min_kernel(const float* __restrict__ a,
                        const float* __restrict__ b,
                        const int* __restrict__ a_idx,
                        const int* __restrict__ b_idx,
                        unsigned* __restrict__ minarr,
                        int N, int a_chunks) {
    __shared__ float4 tile[BPTS];
    const int bid = blockIdx.x;
    const int ac  = bid % a_chunks;   // which a-chunk of 2048 points
    const int bc  = bid / a_chunks;   // which b-chunk of 128 points
    const int tid = threadIdx.x;

    // Stage this block's 128 b-points into LDS as (-2bx,-2by,-2bz,||b||^2)
    if (tid < BPTS) {
        int j  = bc * BPTS + tid;
        int bi = b_idx[j];
        float bx = b[bi], by = b[N + bi], bz = b[2 * N + bi];
        tile[tid] = make_float4(-2.f * bx, -2.f * by, -2.f * bz,
                                bx * bx + by * by + bz * bz);
    }
    __syncthreads();

    float ax[NPTS_A], ay[NPTS_A], az[NPTS_A], mn[NPTS_A];
    int   ii[NPTS_A];
#pragma unroll
    for (int m = 0; m < NPTS_A; ++m) {
        int i = ac * (BLOCK * NPTS_A) + m * BLOCK + tid;  // coalesced a_idx reads
        ii[m] = i;
        int ai = a_idx[i];
        ax[m] = a[ai]; ay[m] = a[N + ai]; az[m] = a[2 * N + ai];
        mn[m] = 3.4e38f;
    }

    // Main loop: 1 broadcast ds_read_b128 per k serves 8 a-points x 4 ops
    for (int k = 0; k < BPTS; ++k) {
        float4 t = tile[k];
#pragma unroll
        for (int m = 0; m < NPTS_A; ++m) {
            float c = fmaf(t.x, ax[m], fmaf(t.y, ay[m], fmaf(t.z, az[m], t.w)));
            mn[m] = fminf(mn[m], c);
        }
    }

#pragma unroll
    for (int m = 0; m < NPTS_A; ++m)
        atomicMin(&minarr[ii[m]], enc_f32(mn[m]));
}

__global__ __launch_bounds__(BLOCK)
void chamfer_reduce_kernel(const float* __restrict__ a,
                           const int* __restrict__ a_idx,
                           const unsigned* __restrict__ minarr,
                           float* __restrict__ out, int N, int n) {
    int i = blockIdx.x * blockDim.x + threadIdx.x;
    float v = 0.f;
    if (i < n) {
        float f  = dec_f32(minarr[i]);
        int   ai = a_idx[i];
        float ax = a[ai], ay = a[N + ai], az = a[2 * N + ai];
        v = f + ax * ax + ay * ay + az * az;
    }
    // wave-64 reduction
#pragma unroll
    for (int off = 32; off > 0; off >>= 1)
        v += __shfl_down(v, off, 64);
    if ((threadIdx.x & 63) == 0)
        atomicAdd(out, v);
}

extern "C" void kernel_launch(void* const* d_in, const int* in_sizes, int n_in,
                              void* d_out, int out_size, void* d_ws, size_t ws_size,
                              hipStream_t stream) {
    const float* a     = (const float*)d_in[0];
    const float* b     = (const float*)d_in[1];
    const int*   a_idx = (const int*)d_in[2];
    const int*   b_idx = (const int*)d_in[3];
    float*       out   = (float*)d_out;

    const int N = in_sizes[0] / 3;   // 16384 points in a/b
    const int n = in_sizes[2];       // 8192 samples

    unsigned* minarr = (unsigned*)d_ws;

    // Init: minarr = 0xFFFFFFFF (encoded +max), out = 0
    hipMemsetAsync(minarr, 0xFF, (size_t)n * sizeof(unsigned), stream);
    hipMemsetAsync(out, 0, sizeof(float), stream);

    const int a_chunks = n / (BLOCK * NPTS_A);  // 4
    const int b_chunks = n / BPTS;              // 64
    chamfer_min_kernel<<<a_chunks * b_chunks, BLOCK, 0, stream>>>(
        a, b, a_idx, b_idx, minarr, N, a_chunks);

    chamfer_reduce_kernel<<<(n + BLOCK - 1) / BLOCK, BLOCK, 0, stream>>>(
        a, a_idx, minarr, out, N, n);
}